// Round 1
// 518.584 us; speedup vs baseline: 1.0023x; 1.0023x over previous
//
#include <hip/hip_runtime.h>
#include <stdint.h>

typedef unsigned short u16;
typedef unsigned int u32;
typedef __bf16 bf16x8 __attribute__((ext_vector_type(8)));
typedef float f32x4 __attribute__((ext_vector_type(4)));

#define N_ATOMS 512
#define BDIM 14
#define BB 196          // 14*14
#define FDIM 128
#define HROW 7168       // 512*14
#define NPAIR 130816
#define ROWS 64         // pairs (or atoms) per block
#define NPBLK (NPAIR / ROWS)            // 2044 pair blocks
#define NBLK  (NPBLK + N_ATOMS / ROWS)  // + 8 diag blocks = 2052
#define HALFU (ROWS * BB / 2)           // 6272 float2 units per block tile

// frag-ordered bf16 weights in ws (u16 element offsets)
#define OFF_W1F   0         // 8 ks * 16 nt * 512
#define OFF_W2F   65536     // 8 ks * 13 nt * 512
#define OFF_WO1F  118784    // 12 ks * 16 nt * 512
#define OFF_WO2F  217088    // 8 ks * 13 nt * 512
#define WS_ELEMS  270336

__device__ __forceinline__ float b2f(u16 u) {
    union { u32 u; float f; } c; c.u = ((u32)u) << 16; return c.f;
}
__device__ __forceinline__ u16 fb(float f) {   // fp32 -> bf16 bits, RTNE
    union { float f; u32 u; } c; c.f = f;
    u32 r = c.u + 0x7fff + ((c.u >> 16) & 1);
    return (u16)(r >> 16);
}
__device__ __forceinline__ bf16x8 ld16b(const u16* p) {
    return *(const bf16x8*)(const void*)p;
}
// load 8 fp32 (32B, aligned) and convert to a bf16x8 fragment
__device__ __forceinline__ bf16x8 ldcvt8(const float* p) {
    const float4 a = *(const float4*)(const void*)p;
    const float4 b = *(const float4*)(const void*)(p + 4);
    bf16x8 r;
    r[0] = (__bf16)a.x; r[1] = (__bf16)a.y; r[2] = (__bf16)a.z; r[3] = (__bf16)a.w;
    r[4] = (__bf16)b.x; r[5] = (__bf16)b.y; r[6] = (__bf16)b.z; r[7] = (__bf16)b.w;
    return r;
}

// ---- reorder fp32 weights into bf16 MFMA fragment order:
// Wf[ks][nt][lane][j] = bf16(W[ks*32 + (lane>>4)*8 + j][nt*16 + (lane&15)]), zero-padded cols
__global__ void prep_kernel(const float* __restrict__ W1, const float* __restrict__ W2,
                            const float* __restrict__ Wo1, const float* __restrict__ Wo2,
                            u16* __restrict__ ws) {
    int gid = blockIdx.x * 256 + threadIdx.x;
    const float* src; int idx, NT, Ncols, Nreal;
    if (gid < OFF_W2F)       { idx = gid;             src = W1;  NT = 16; Ncols = 256; Nreal = 256; }
    else if (gid < OFF_WO1F) { idx = gid - OFF_W2F;   src = W2;  NT = 13; Ncols = 196; Nreal = 196; }
    else if (gid < OFF_WO2F) { idx = gid - OFF_WO1F;  src = Wo1; NT = 16; Ncols = 256; Nreal = 256; }
    else                     { idx = gid - OFF_WO2F;  src = Wo2; NT = 13; Ncols = 196; Nreal = 196; }
    int jj   = idx & 7;
    int lane = (idx >> 3) & 63;
    int tile = idx >> 9;
    int nt = tile % NT;
    int ks = tile / NT;
    int k = ks * 32 + ((lane >> 4) << 3) + jj;
    int n = nt * 16 + (lane & 15);
    ws[gid] = (n < Nreal) ? fb(src[k * Ncols + n]) : (u16)0;
}

// ---- fused MLP + scatter. blocks [0,2044): 64 pairs each; blocks [2044,2052): 64 diag rows.
// 64-row tile: sH = 64*264*2 = 33.8 KB  -> 4 blocks/CU (vs 2 at 128-row tile)
__global__ __launch_bounds__(256, 4)
void ham_main(const float* __restrict__ nodes, const float* __restrict__ edges,
              const float* __restrict__ atomb, const float* __restrict__ ovl,
              const float* __restrict__ b1v, const float* __restrict__ b2v,
              const float* __restrict__ bo1, const float* __restrict__ bo2,
              const int* __restrict__ pair_i, const int* __restrict__ pair_j,
              const u16* __restrict__ ws, float* __restrict__ out)
{
    __shared__ u16 sH[ROWS * 264];   // stage-1 H tile, reused as Out tile [64][196]
    __shared__ int sI[ROWS], sJ[ROWS];
    const int tid = threadIdx.x;
    const int w = tid >> 6, lane = tid & 63;
    const int q = lane >> 4, l15 = lane & 15;
    const int bid = blockIdx.x;
    const bool isPair = bid < NPBLK;

    // per-wave: all 4 waves cover the same 64 rows; wave w owns hidden quarter w.
    u32 offA[4], offB[4], offE[4];   // fp32-element offsets; bases chosen per k-segment
    int KS1;
    const u16 *WAf, *WBf;
    const float *bias1, *bias2;
    const float *seg1base;           // nodes (pair: node_j) or edges (diag: e_ii)

    if (isPair) {
        const int pbase = bid * ROWS;
        KS1 = 12; WAf = ws + OFF_WO1F; WBf = ws + OFF_WO2F; bias1 = bo1; bias2 = bo2;
        seg1base = nodes;
        if (tid < ROWS) { int p = pbase + tid; sI[tid] = pair_i[p]; sJ[tid] = pair_j[p]; }
        #pragma unroll
        for (int pp = 0; pp < 4; ++pp) {
            int p = pbase + pp * 16 + l15;
            int i = pair_i[p], j = pair_j[p];
            offA[pp] = (u32)i * FDIM;
            offB[pp] = (u32)j * FDIM;
            offE[pp] = ((u32)i * N_ATOMS + (u32)j) * FDIM;
        }
    } else {
        const int nbase = (bid - NPBLK) * ROWS;
        KS1 = 8; WAf = ws + OFF_W1F; WBf = ws + OFF_W2F; bias1 = b1v; bias2 = b2v;
        seg1base = edges;
        #pragma unroll
        for (int pp = 0; pp < 4; ++pp) {
            int nn = nbase + pp * 16 + l15;
            offA[pp] = (u32)nn * FDIM;
            offB[pp] = ((u32)nn * N_ATOMS + (u32)nn) * FDIM;
            offE[pp] = offB[pp];
        }
    }

    // ======== stage 1: D[hidden][row] = W^T * X^T  (A = frag-order W, B = gathered X rows)
    f32x4 acc[4][4];
    #pragma unroll
    for (int a = 0; a < 4; ++a)
        #pragma unroll
        for (int b = 0; b < 4; ++b)
            acc[a][b] = (f32x4){0.f, 0.f, 0.f, 0.f};

    for (int ks = 0; ks < KS1; ++ks) {
        const int seg = ks >> 2;
        const int koff = (ks & 3) * 32 + q * 8;
        const float* bse = (seg == 0) ? nodes : (seg == 1) ? seg1base : edges;
        bf16x8 bfr[4];
        #pragma unroll
        for (int pp = 0; pp < 4; ++pp) {
            const u32 off = (seg == 0) ? offA[pp] : (seg == 1) ? offB[pp] : offE[pp];
            bfr[pp] = ldcvt8(bse + off + koff);
        }
        const u16* ap = WAf + ((size_t)((ks * 16 + w * 4) * 64 + lane)) * 8;
        #pragma unroll
        for (int hh = 0; hh < 4; ++hh) {
            bf16x8 afr = ld16b(ap + (size_t)hh * 512);
            #pragma unroll
            for (int pp = 0; pp < 4; ++pp)
                acc[hh][pp] = __builtin_amdgcn_mfma_f32_16x16x32_bf16(afr, bfr[pp], acc[hh][pp], 0, 0, 0);
        }
    }

    // bias + SiLU, write H[row][hidden] bf16 (lane holds 4 consecutive hidden -> one 8B write)
    #pragma unroll
    for (int hh = 0; hh < 4; ++hh) {
        const int h0 = w * 64 + hh * 16 + q * 4;
        const float bb0 = bias1[h0], bb1 = bias1[h0 + 1];
        const float bb2 = bias1[h0 + 2], bb3 = bias1[h0 + 3];
        #pragma unroll
        for (int pp = 0; pp < 4; ++pp) {
            const int row = pp * 16 + l15;
            float x0 = acc[hh][pp][0] + bb0, x1 = acc[hh][pp][1] + bb1;
            float x2 = acc[hh][pp][2] + bb2, x3 = acc[hh][pp][3] + bb3;
            float s0 = x0 / (1.f + __expf(-x0)), s1 = x1 / (1.f + __expf(-x1));
            float s2 = x2 / (1.f + __expf(-x2)), s3 = x3 / (1.f + __expf(-x3));
            uint2 pk;
            pk.x = (u32)fb(s0) | ((u32)fb(s1) << 16);
            pk.y = (u32)fb(s2) | ((u32)fb(s3) << 16);
            *(uint2*)(void*)&sH[row * 264 + h0] = pk;
        }
    }
    __syncthreads();

    // ======== stage 2: D[row][e] = H * W2  (A = H from LDS, B = frag-order W2, N padded to 208)
    f32x4 acc2[13];
    #pragma unroll
    for (int n = 0; n < 13; ++n)
        acc2[n] = (f32x4){0.f, 0.f, 0.f, 0.f};

    const int row2 = w * 16 + l15;   // each wave owns 16 rows
    for (int ks = 0; ks < 8; ++ks) {
        bf16x8 a2 = ld16b(&sH[row2 * 264 + ks * 32 + q * 8]);
        const u16* bp = WBf + ((size_t)((ks * 13) * 64 + lane)) * 8;
        #pragma unroll
        for (int nt = 0; nt < 13; ++nt) {
            bf16x8 bfr = ld16b(bp + (size_t)nt * 512);
            acc2[nt] = __builtin_amdgcn_mfma_f32_16x16x32_bf16(a2, bfr, acc2[nt], 0, 0, 0);
        }
    }
    __syncthreads();   // all H reads done; reuse sH as Out tile [64][196] bf16

    // ======== fused epilogue: bias + overlap/atom-block add, single bf16 rounding
    u16* sOut = sH;
    const float* addsrc = isPair ? (ovl + (size_t)bid * ROWS * BB)
                                 : (atomb + (size_t)(bid - NPBLK) * ROWS * BB);
    const int pr = w * 16 + q * 4;
    #pragma unroll
    for (int nt = 0; nt < 13; ++nt) {
        const int e = nt * 16 + l15;
        if (e < BB) {
            const float be = bias2[e];
            #pragma unroll
            for (int r = 0; r < 4; ++r) {
                float v = acc2[nt][r] + be + addsrc[(size_t)(pr + r) * BB + e];
                sOut[(pr + r) * BB + e] = fb(v);
            }
        }
    }
    __syncthreads();

    if (isPair) {
        // direct blocks H[i*14+a][j*14+b]: fixed a -> consecutive units are contiguous cols
        for (int u = tid; u < HALFU; u += 256) {
            const int a = u / 448;            // 448 = 64 pairs * 7 col-pairs
            const int r = u - a * 448;
            const int pl = r / 7;
            const int c2 = (r - pl * 7) * 2;
            const int i = sI[pl], j = sJ[pl];
            u32 v = *(const u32*)(const void*)(sOut + pl * BB + a * 14 + c2);
            float2 o; o.x = b2f((u16)v); o.y = b2f((u16)(v >> 16));
            size_t addr = (size_t)(i * 14 + a) * HROW + j * 14 + c2;
            *(float2*)(void*)(out + addr) = o;
        }
        // transposed blocks H[j*14+b][i*14+a]
        for (int u = tid; u < HALFU; u += 256) {
            const int pl = u / 98;
            const int r = u - pl * 98;
            const int b = r / 7;
            const int a2i = (r - b * 7) * 2;
            const int i = sI[pl], j = sJ[pl];
            float2 o;
            o.x = b2f(sOut[pl * BB + a2i * 14 + b]);
            o.y = b2f(sOut[pl * BB + (a2i + 1) * 14 + b]);
            size_t addr = (size_t)(j * 14 + b) * HROW + i * 14 + a2i;
            *(float2*)(void*)(out + addr) = o;
        }
    } else {
        const int nbase = (bid - NPBLK) * ROWS;
        for (int u = tid; u < HALFU; u += 256) {
            const int a = u / 448;
            const int r = u - a * 448;
            const int pl = r / 7;
            const int c2 = (r - pl * 7) * 2;
            const int nn = nbase + pl;
            u32 v = *(const u32*)(const void*)(sOut + pl * BB + a * 14 + c2);
            float2 o; o.x = b2f((u16)v); o.y = b2f((u16)(v >> 16));
            size_t addr = (size_t)(nn * 14 + a) * HROW + nn * 14 + c2;
            *(float2*)(void*)(out + addr) = o;
        }
    }
}

extern "C" void kernel_launch(void* const* d_in, const int* in_sizes, int n_in,
                              void* d_out, int out_size, void* d_ws, size_t ws_size,
                              hipStream_t stream) {
    const float* nodes = (const float*)d_in[0];
    const float* edges = (const float*)d_in[1];
    const float* atomb = (const float*)d_in[2];
    const float* ovl   = (const float*)d_in[3];
    const float* W1    = (const float*)d_in[4];
    const float* b1    = (const float*)d_in[5];
    const float* W2    = (const float*)d_in[6];
    const float* b2    = (const float*)d_in[7];
    const float* Wo1   = (const float*)d_in[8];
    const float* bo1   = (const float*)d_in[9];
    const float* Wo2   = (const float*)d_in[10];
    const float* bo2   = (const float*)d_in[11];
    const int* pi      = (const int*)d_in[12];
    const int* pj      = (const int*)d_in[13];
    u16* ws    = (u16*)d_ws;
    float* out = (float*)d_out;

    prep_kernel<<<WS_ELEMS / 256, 256, 0, stream>>>(W1, W2, Wo1, Wo2, ws);
    ham_main<<<NBLK, 256, 0, stream>>>(nodes, edges, atomb, ovl,
                                       b1, b2, bo1, bo2, pi, pj, ws, out);
}

// Round 2
// 512.973 us; speedup vs baseline: 1.0133x; 1.0109x over previous
//
#include <hip/hip_runtime.h>
#include <stdint.h>

typedef unsigned short u16;
typedef unsigned int u32;
typedef __bf16 bf16x8 __attribute__((ext_vector_type(8)));
typedef float f32x4 __attribute__((ext_vector_type(4)));

#define N_ATOMS 512
#define BDIM 14
#define BB 196          // 14*14
#define FDIM 128
#define HROW 7168       // 512*14
#define NPAIR 130816
#define ROWS 64         // pairs (or atoms) per block
#define NPBLK (NPAIR / ROWS)            // 2044 pair blocks
#define NBLK  (NPBLK + N_ATOMS / ROWS)  // + 8 diag blocks = 2052
#define HALFU (ROWS * BB / 2)           // 6272 float2 units per block tile

// frag-ordered bf16 weights in ws (u16 element offsets)
#define OFF_W1F   0         // 8 ks * 16 nt * 512
#define OFF_W2F   65536     // 8 ks * 13 nt * 512
#define OFF_WO1F  118784    // 12 ks * 16 nt * 512
#define OFF_WO2F  217088    // 8 ks * 13 nt * 512
#define WS_ELEMS  270336

__device__ __forceinline__ float b2f(u16 u) {
    union { u32 u; float f; } c; c.u = ((u32)u) << 16; return c.f;
}
__device__ __forceinline__ u16 fb(float f) {   // fp32 -> bf16 bits, RTNE
    union { float f; u32 u; } c; c.f = f;
    u32 r = c.u + 0x7fff + ((c.u >> 16) & 1);
    return (u16)(r >> 16);
}
__device__ __forceinline__ bf16x8 ld16b(const u16* p) {
    return *(const bf16x8*)(const void*)p;
}
// load 8 fp32 (32B, aligned) and convert to a bf16x8 fragment
__device__ __forceinline__ bf16x8 ldcvt8(const float* p) {
    const float4 a = *(const float4*)(const void*)p;
    const float4 b = *(const float4*)(const void*)(p + 4);
    bf16x8 r;
    r[0] = (__bf16)a.x; r[1] = (__bf16)a.y; r[2] = (__bf16)a.z; r[3] = (__bf16)a.w;
    r[4] = (__bf16)b.x; r[5] = (__bf16)b.y; r[6] = (__bf16)b.z; r[7] = (__bf16)b.w;
    return r;
}

// ---- reorder fp32 weights into bf16 MFMA fragment order:
// Wf[ks][nt][lane][j] = bf16(W[ks*32 + (lane>>4)*8 + j][nt*16 + (lane&15)]), zero-padded cols
__global__ void prep_kernel(const float* __restrict__ W1, const float* __restrict__ W2,
                            const float* __restrict__ Wo1, const float* __restrict__ Wo2,
                            u16* __restrict__ ws) {
    int gid = blockIdx.x * 256 + threadIdx.x;
    const float* src; int idx, NT, Ncols, Nreal;
    if (gid < OFF_W2F)       { idx = gid;             src = W1;  NT = 16; Ncols = 256; Nreal = 256; }
    else if (gid < OFF_WO1F) { idx = gid - OFF_W2F;   src = W2;  NT = 13; Ncols = 196; Nreal = 196; }
    else if (gid < OFF_WO2F) { idx = gid - OFF_WO1F;  src = Wo1; NT = 16; Ncols = 256; Nreal = 256; }
    else                     { idx = gid - OFF_WO2F;  src = Wo2; NT = 13; Ncols = 196; Nreal = 196; }
    int jj   = idx & 7;
    int lane = (idx >> 3) & 63;
    int tile = idx >> 9;
    int nt = tile % NT;
    int ks = tile / NT;
    int k = ks * 32 + ((lane >> 4) << 3) + jj;
    int n = nt * 16 + (lane & 15);
    ws[gid] = (n < Nreal) ? fb(src[k * Ncols + n]) : (u16)0;
}

// ---- MLP core, compile-time K so stage-1 gather loads pipeline deeply
template<int KS1>
__device__ __forceinline__ void mlp_tile(
    const float* __restrict__ nodes, const float* __restrict__ edges,
    const float* __restrict__ bse1,                 // seg-1 base: nodes (pair) / edges (diag)
    uint4 oA, uint4 oB, uint4 oE,                   // fp32-elem offsets per pp
    const u16* __restrict__ WAf, const u16* __restrict__ WBf,
    const float* __restrict__ bias1, const float* __restrict__ bias2,
    const float* __restrict__ addsrc,               // ovl / atomb tile base
    u16* sH, const int w, const int lane, const int q, const int l15)
{
    // ======== stage 1: D[hidden][row] = W^T * X^T
    f32x4 acc[4][4];
    #pragma unroll
    for (int a = 0; a < 4; ++a)
        #pragma unroll
        for (int b = 0; b < 4; ++b)
            acc[a][b] = (f32x4){0.f, 0.f, 0.f, 0.f};

    #pragma unroll
    for (int ks = 0; ks < KS1; ++ks) {
        const int seg = ks >> 2;                    // compile-time after unroll
        const int koff = (ks & 3) * 32 + q * 8;
        const float* bse = (seg == 0) ? nodes : (seg == 1) ? bse1 : edges;
        const uint4 ov  = (seg == 0) ? oA   : (seg == 1) ? oB   : oE;
        bf16x8 bf0 = ldcvt8(bse + ov.x + koff);
        bf16x8 bf1 = ldcvt8(bse + ov.y + koff);
        bf16x8 bf2 = ldcvt8(bse + ov.z + koff);
        bf16x8 bf3 = ldcvt8(bse + ov.w + koff);
        const u16* ap = WAf + (size_t)((ks * 16 + w * 4) * 64 + lane) * 8;
        #pragma unroll
        for (int hh = 0; hh < 4; ++hh) {
            bf16x8 afr = ld16b(ap + (size_t)hh * 512);
            acc[hh][0] = __builtin_amdgcn_mfma_f32_16x16x32_bf16(afr, bf0, acc[hh][0], 0, 0, 0);
            acc[hh][1] = __builtin_amdgcn_mfma_f32_16x16x32_bf16(afr, bf1, acc[hh][1], 0, 0, 0);
            acc[hh][2] = __builtin_amdgcn_mfma_f32_16x16x32_bf16(afr, bf2, acc[hh][2], 0, 0, 0);
            acc[hh][3] = __builtin_amdgcn_mfma_f32_16x16x32_bf16(afr, bf3, acc[hh][3], 0, 0, 0);
        }
    }

    // bias + SiLU, write H[row][hidden] bf16 (lane holds 4 consecutive hidden -> one 8B write)
    #pragma unroll
    for (int hh = 0; hh < 4; ++hh) {
        const int h0 = w * 64 + hh * 16 + q * 4;
        const float bb0 = bias1[h0], bb1 = bias1[h0 + 1];
        const float bb2 = bias1[h0 + 2], bb3 = bias1[h0 + 3];
        #pragma unroll
        for (int pp = 0; pp < 4; ++pp) {
            const int row = pp * 16 + l15;
            float x0 = acc[hh][pp][0] + bb0, x1 = acc[hh][pp][1] + bb1;
            float x2 = acc[hh][pp][2] + bb2, x3 = acc[hh][pp][3] + bb3;
            float s0 = x0 / (1.f + __expf(-x0)), s1 = x1 / (1.f + __expf(-x1));
            float s2 = x2 / (1.f + __expf(-x2)), s3 = x3 / (1.f + __expf(-x3));
            uint2 pk;
            pk.x = (u32)fb(s0) | ((u32)fb(s1) << 16);
            pk.y = (u32)fb(s2) | ((u32)fb(s3) << 16);
            *(uint2*)(void*)&sH[row * 264 + h0] = pk;
        }
    }
    __syncthreads();

    // ======== stage 2: D[row][e] = H * W2  (A = H from LDS, B = frag-order W2)
    f32x4 acc2[13];
    #pragma unroll
    for (int n = 0; n < 13; ++n)
        acc2[n] = (f32x4){0.f, 0.f, 0.f, 0.f};

    const int row2 = w * 16 + l15;   // each wave owns 16 rows
    #pragma unroll
    for (int ks = 0; ks < 8; ++ks) {
        bf16x8 a2 = ld16b(&sH[row2 * 264 + ks * 32 + q * 8]);
        const u16* bp = WBf + (size_t)((ks * 13) * 64 + lane) * 8;
        #pragma unroll
        for (int nt = 0; nt < 13; ++nt) {
            bf16x8 bfr = ld16b(bp + (size_t)nt * 512);
            acc2[nt] = __builtin_amdgcn_mfma_f32_16x16x32_bf16(a2, bfr, acc2[nt], 0, 0, 0);
        }
    }
    __syncthreads();   // all H reads done; reuse sH as Out tile [64][196] bf16

    // ======== fused epilogue: bias + overlap/atom-block add, single bf16 rounding
    u16* sOut = sH;
    const int pr = w * 16 + q * 4;
    #pragma unroll
    for (int nt = 0; nt < 13; ++nt) {
        const int e = nt * 16 + l15;
        if (e < BB) {
            const float be = bias2[e];
            #pragma unroll
            for (int r = 0; r < 4; ++r) {
                float v = acc2[nt][r] + be + addsrc[(size_t)(pr + r) * BB + e];
                sOut[(pr + r) * BB + e] = fb(v);
            }
        }
    }
    __syncthreads();
}

// ---- fused MLP + scatter. blocks [0,2044): 64 pairs each; blocks [2044,2052): 64 diag rows.
// 64-row tile: sH = 64*264*2 = 33.8 KB  -> 4 blocks/CU
__global__ __launch_bounds__(256, 4)
void ham_main(const float* __restrict__ nodes, const float* __restrict__ edges,
              const float* __restrict__ atomb, const float* __restrict__ ovl,
              const float* __restrict__ b1v, const float* __restrict__ b2v,
              const float* __restrict__ bo1, const float* __restrict__ bo2,
              const int* __restrict__ pair_i, const int* __restrict__ pair_j,
              const u16* __restrict__ ws, float* __restrict__ out)
{
    __shared__ u16 sH[ROWS * 264];   // stage-1 H tile, reused as Out tile [64][196]
    __shared__ int sI[ROWS], sJ[ROWS];
    const int tid = threadIdx.x;
    const int w = tid >> 6, lane = tid & 63;
    const int q = lane >> 4, l15 = lane & 15;
    const int bid = blockIdx.x;
    const bool isPair = bid < NPBLK;

    if (isPair) {
        const int pbase = bid * ROWS;
        if (tid < ROWS) { int p = pbase + tid; sI[tid] = pair_i[p]; sJ[tid] = pair_j[p]; }
        uint4 oA, oB, oE;
        {
            int p, i, j;
            p = pbase + 0 * 16 + l15; i = pair_i[p]; j = pair_j[p];
            oA.x = (u32)i * FDIM; oB.x = (u32)j * FDIM; oE.x = ((u32)i * N_ATOMS + (u32)j) * FDIM;
            p = pbase + 1 * 16 + l15; i = pair_i[p]; j = pair_j[p];
            oA.y = (u32)i * FDIM; oB.y = (u32)j * FDIM; oE.y = ((u32)i * N_ATOMS + (u32)j) * FDIM;
            p = pbase + 2 * 16 + l15; i = pair_i[p]; j = pair_j[p];
            oA.z = (u32)i * FDIM; oB.z = (u32)j * FDIM; oE.z = ((u32)i * N_ATOMS + (u32)j) * FDIM;
            p = pbase + 3 * 16 + l15; i = pair_i[p]; j = pair_j[p];
            oA.w = (u32)i * FDIM; oB.w = (u32)j * FDIM; oE.w = ((u32)i * N_ATOMS + (u32)j) * FDIM;
        }
        mlp_tile<12>(nodes, edges, nodes, oA, oB, oE,
                     ws + OFF_WO1F, ws + OFF_WO2F, bo1, bo2,
                     ovl + (size_t)pbase * BB, sH, w, lane, q, l15);

        u16* sOut = sH;
        // direct blocks H[i*14+a][j*14+b]: fixed a -> consecutive units are contiguous cols
        for (int u = tid; u < HALFU; u += 256) {
            const int a = u / 448;            // 448 = 64 pairs * 7 col-pairs
            const int r = u - a * 448;
            const int pl = r / 7;
            const int c2 = (r - pl * 7) * 2;
            const int i = sI[pl], j = sJ[pl];
            u32 v = *(const u32*)(const void*)(sOut + pl * BB + a * 14 + c2);
            float2 o; o.x = b2f((u16)v); o.y = b2f((u16)(v >> 16));
            size_t addr = (size_t)(i * 14 + a) * HROW + j * 14 + c2;
            *(float2*)(void*)(out + addr) = o;
        }
        // transposed blocks H[j*14+b][i*14+a]
        for (int u = tid; u < HALFU; u += 256) {
            const int pl = u / 98;
            const int r = u - pl * 98;
            const int b = r / 7;
            const int a2i = (r - b * 7) * 2;
            const int i = sI[pl], j = sJ[pl];
            float2 o;
            o.x = b2f(sOut[pl * BB + a2i * 14 + b]);
            o.y = b2f(sOut[pl * BB + (a2i + 1) * 14 + b]);
            size_t addr = (size_t)(j * 14 + b) * HROW + i * 14 + a2i;
            *(float2*)(void*)(out + addr) = o;
        }
    } else {
        const int nbase = (bid - NPBLK) * ROWS;
        uint4 oA, oB;
        {
            int nn;
            nn = nbase + 0 * 16 + l15;
            oA.x = (u32)nn * FDIM; oB.x = ((u32)nn * N_ATOMS + (u32)nn) * FDIM;
            nn = nbase + 1 * 16 + l15;
            oA.y = (u32)nn * FDIM; oB.y = ((u32)nn * N_ATOMS + (u32)nn) * FDIM;
            nn = nbase + 2 * 16 + l15;
            oA.z = (u32)nn * FDIM; oB.z = ((u32)nn * N_ATOMS + (u32)nn) * FDIM;
            nn = nbase + 3 * 16 + l15;
            oA.w = (u32)nn * FDIM; oB.w = ((u32)nn * N_ATOMS + (u32)nn) * FDIM;
        }
        mlp_tile<8>(nodes, edges, edges, oA, oB, oB,
                    ws + OFF_W1F, ws + OFF_W2F, b1v, b2v,
                    atomb + (size_t)nbase * BB, sH, w, lane, q, l15);

        u16* sOut = sH;
        for (int u = tid; u < HALFU; u += 256) {
            const int a = u / 448;
            const int r = u - a * 448;
            const int pl = r / 7;
            const int c2 = (r - pl * 7) * 2;
            const int nn = nbase + pl;
            u32 v = *(const u32*)(const void*)(sOut + pl * BB + a * 14 + c2);
            float2 o; o.x = b2f((u16)v); o.y = b2f((u16)(v >> 16));
            size_t addr = (size_t)(nn * 14 + a) * HROW + nn * 14 + c2;
            *(float2*)(void*)(out + addr) = o;
        }
    }
}

extern "C" void kernel_launch(void* const* d_in, const int* in_sizes, int n_in,
                              void* d_out, int out_size, void* d_ws, size_t ws_size,
                              hipStream_t stream) {
    const float* nodes = (const float*)d_in[0];
    const float* edges = (const float*)d_in[1];
    const float* atomb = (const float*)d_in[2];
    const float* ovl   = (const float*)d_in[3];
    const float* W1    = (const float*)d_in[4];
    const float* b1    = (const float*)d_in[5];
    const float* W2    = (const float*)d_in[6];
    const float* b2    = (const float*)d_in[7];
    const float* Wo1   = (const float*)d_in[8];
    const float* bo1   = (const float*)d_in[9];
    const float* Wo2   = (const float*)d_in[10];
    const float* bo2   = (const float*)d_in[11];
    const int* pi      = (const int*)d_in[12];
    const int* pj      = (const int*)d_in[13];
    u16* ws    = (u16*)d_ws;
    float* out = (float*)d_out;

    prep_kernel<<<WS_ELEMS / 256, 256, 0, stream>>>(W1, W2, Wo1, Wo2, ws);
    ham_main<<<NBLK, 256, 0, stream>>>(nodes, edges, atomb, ovl,
                                       b1, b2, bo1, bo2, pi, pj, ws, out);
}

// Round 3
// 504.178 us; speedup vs baseline: 1.0309x; 1.0174x over previous
//
#include <hip/hip_runtime.h>
#include <stdint.h>

typedef unsigned short u16;
typedef unsigned int u32;
typedef __bf16 bf16x8 __attribute__((ext_vector_type(8)));
typedef float f32x4 __attribute__((ext_vector_type(4)));

#define N_ATOMS 512
#define BB 196          // 14*14
#define FDIM 128
#define HROW 7168       // 512*14
#define NPAIR 130816
#define ROWS 64         // pairs (or atoms) per block
#define NPBLK (NPAIR / ROWS)            // 2044 pair blocks
#define NBLK  (NPBLK + N_ATOMS / ROWS)  // + 8 diag blocks = 2052
#define HALFU (ROWS * BB / 2)           // 6272 float2 units per block tile

#define XS 392          // sX row stride in u16 (384 data + 8 pad -> 196 dw = 4 mod 32)
#define HS 264          // sH row stride in u16

// frag-ordered bf16 weights in ws (u16 element offsets)
#define OFF_W1F   0         // 8 ks * 16 nt * 512
#define OFF_W2F   65536     // 8 ks * 13 nt * 512
#define OFF_WO1F  118784    // 12 ks * 16 nt * 512
#define OFF_WO2F  217088    // 8 ks * 13 nt * 512
#define WS_ELEMS  270336

__device__ __forceinline__ float b2f(u16 u) {
    union { u32 u; float f; } c; c.u = ((u32)u) << 16; return c.f;
}
__device__ __forceinline__ u16 fb(float f) {   // fp32 -> bf16 bits, RTNE
    union { float f; u32 u; } c; c.f = f;
    u32 r = c.u + 0x7fff + ((c.u >> 16) & 1);
    return (u16)(r >> 16);
}
__device__ __forceinline__ bf16x8 ld16b(const u16* p) {
    return *(const bf16x8*)(const void*)p;
}
// pack 4 fp32 -> 4 bf16 (RTNE, same as (__bf16) cast used throughout)
__device__ __forceinline__ uint2 pk4(float4 v) {
    union { __bf16 h[4]; uint2 u; } c;
    c.h[0] = (__bf16)v.x; c.h[1] = (__bf16)v.y;
    c.h[2] = (__bf16)v.z; c.h[3] = (__bf16)v.w;
    return c.u;
}

// ---- reorder fp32 weights into bf16 MFMA fragment order:
// Wf[ks][nt][lane][j] = bf16(W[ks*32 + (lane>>4)*8 + j][nt*16 + (lane&15)]), zero-padded cols
__global__ void prep_kernel(const float* __restrict__ W1, const float* __restrict__ W2,
                            const float* __restrict__ Wo1, const float* __restrict__ Wo2,
                            u16* __restrict__ ws) {
    int gid = blockIdx.x * 256 + threadIdx.x;
    const float* src; int idx, NT, Ncols, Nreal;
    if (gid < OFF_W2F)       { idx = gid;             src = W1;  NT = 16; Ncols = 256; Nreal = 256; }
    else if (gid < OFF_WO1F) { idx = gid - OFF_W2F;   src = W2;  NT = 13; Ncols = 196; Nreal = 196; }
    else if (gid < OFF_WO2F) { idx = gid - OFF_WO1F;  src = Wo1; NT = 16; Ncols = 256; Nreal = 256; }
    else                     { idx = gid - OFF_WO2F;  src = Wo2; NT = 13; Ncols = 196; Nreal = 196; }
    int jj   = idx & 7;
    int lane = (idx >> 3) & 63;
    int tile = idx >> 9;
    int nt = tile % NT;
    int ks = tile / NT;
    int k = ks * 32 + ((lane >> 4) << 3) + jj;
    int n = nt * 16 + (lane & 15);
    ws[gid] = (n < Nreal) ? fb(src[k * Ncols + n]) : (u16)0;
}

// ---- MLP core. X rows are STAGED into LDS with coalesced loads (16 dense
// lines/instr) instead of per-lane 16-row gathers (32 scattered trans/instr).
// Stage-2 N-tiles are split across waves so each W2 fragment is read once/block.
template<int KS1>
__device__ __forceinline__ void mlp_tile(
    const float* __restrict__ sb0, const float* __restrict__ sb1,
    const float* __restrict__ sb2,                  // per-thread row bases (row = tid>>2)
    const u16* __restrict__ WAf, const u16* __restrict__ WBf,
    const float* __restrict__ bias1, const float* __restrict__ bias2,
    const float* __restrict__ addsrc,               // ovl / atomb tile base
    u16* sX, const int tid)
{
    constexpr int NSEG = KS1 / 4;
    const int w = tid >> 6, lane = tid & 63;
    const int q = lane >> 4, l15 = lane & 15;
    const int srow = tid >> 2, ssub = tid & 3;      // 4 threads cooperate per row

    // ======== stage X rows (bf16) into LDS; per instr: 16 rows x 64B dense
    #pragma unroll
    for (int seg = 0; seg < NSEG; ++seg) {
        const float* rb = (seg == 0) ? sb0 : (seg == 1) ? sb1 : sb2;
        #pragma unroll
        for (int it = 0; it < 8; ++it) {
            const int f0 = it * 16 + ssub * 4;
            const float4 v = *(const float4*)(const void*)(rb + f0);
            *(uint2*)(void*)&sX[srow * XS + seg * 128 + f0] = pk4(v);
        }
    }
    __syncthreads();

    // ======== stage 1: D[hidden][row] = W^T * X^T  (A = frag W, B = X from LDS)
    f32x4 acc[4][4];
    #pragma unroll
    for (int a = 0; a < 4; ++a)
        #pragma unroll
        for (int b = 0; b < 4; ++b)
            acc[a][b] = (f32x4){0.f, 0.f, 0.f, 0.f};

    #pragma unroll
    for (int ks = 0; ks < KS1; ++ks) {
        const int xoff = ks * 32 + q * 8;
        bf16x8 bfr[4];
        #pragma unroll
        for (int pp = 0; pp < 4; ++pp)
            bfr[pp] = ld16b(&sX[(pp * 16 + l15) * XS + xoff]);
        const u16* ap = WAf + (size_t)((ks * 16 + w * 4) * 64 + lane) * 8;
        #pragma unroll
        for (int hh = 0; hh < 4; ++hh) {
            bf16x8 afr = ld16b(ap + (size_t)hh * 512);
            acc[hh][0] = __builtin_amdgcn_mfma_f32_16x16x32_bf16(afr, bfr[0], acc[hh][0], 0, 0, 0);
            acc[hh][1] = __builtin_amdgcn_mfma_f32_16x16x32_bf16(afr, bfr[1], acc[hh][1], 0, 0, 0);
            acc[hh][2] = __builtin_amdgcn_mfma_f32_16x16x32_bf16(afr, bfr[2], acc[hh][2], 0, 0, 0);
            acc[hh][3] = __builtin_amdgcn_mfma_f32_16x16x32_bf16(afr, bfr[3], acc[hh][3], 0, 0, 0);
        }
    }
    __syncthreads();   // all sX reads done; region becomes sH

    // bias + SiLU, write H[row][hidden] bf16 (lane holds 4 consecutive hidden)
    u16* sH = sX;
    #pragma unroll
    for (int hh = 0; hh < 4; ++hh) {
        const int h0 = w * 64 + hh * 16 + q * 4;
        const float bb0 = bias1[h0], bb1 = bias1[h0 + 1];
        const float bb2 = bias1[h0 + 2], bb3 = bias1[h0 + 3];
        #pragma unroll
        for (int pp = 0; pp < 4; ++pp) {
            const int row = pp * 16 + l15;
            float x0 = acc[hh][pp][0] + bb0, x1 = acc[hh][pp][1] + bb1;
            float x2 = acc[hh][pp][2] + bb2, x3 = acc[hh][pp][3] + bb3;
            float s0 = x0 / (1.f + __expf(-x0)), s1 = x1 / (1.f + __expf(-x1));
            float s2 = x2 / (1.f + __expf(-x2)), s3 = x3 / (1.f + __expf(-x3));
            uint2 pk;
            pk.x = (u32)fb(s0) | ((u32)fb(s1) << 16);
            pk.y = (u32)fb(s2) | ((u32)fb(s3) << 16);
            *(uint2*)(void*)&sH[row * HS + h0] = pk;
        }
    }
    __syncthreads();

    // ======== stage 2: D[row][e] = H * W2; wave w owns nt range (4/3/3/3),
    // all 4 row-tiles -> each W2 fragment read exactly once per block.
    const int ntLo = (w == 0) ? 0 : 1 + 3 * w;   // 0,4,7,10
    const int ntN  = (w == 0) ? 4 : 3;

    f32x4 acc2[4][4];   // [mm][local nt]
    #pragma unroll
    for (int a = 0; a < 4; ++a)
        #pragma unroll
        for (int b = 0; b < 4; ++b)
            acc2[a][b] = (f32x4){0.f, 0.f, 0.f, 0.f};

    #pragma unroll
    for (int ks = 0; ks < 8; ++ks) {
        bf16x8 a2[4];
        #pragma unroll
        for (int mm = 0; mm < 4; ++mm)
            a2[mm] = ld16b(&sH[(mm * 16 + l15) * HS + ks * 32 + q * 8]);
        #pragma unroll
        for (int ntl = 0; ntl < 4; ++ntl) {
            if (ntl < ntN) {   // wave-uniform
                const int nt = ntLo + ntl;
                bf16x8 bfr = ld16b(WBf + (size_t)((ks * 13 + nt) * 64 + lane) * 8);
                #pragma unroll
                for (int mm = 0; mm < 4; ++mm)
                    acc2[mm][ntl] = __builtin_amdgcn_mfma_f32_16x16x32_bf16(a2[mm], bfr, acc2[mm][ntl], 0, 0, 0);
            }
        }
    }
    __syncthreads();   // all H reads done; reuse region as Out tile [64][196] bf16

    // ======== fused epilogue: bias + overlap/atom-block add, single bf16 rounding
    u16* sOut = sX;
    #pragma unroll
    for (int ntl = 0; ntl < 4; ++ntl) {
        if (ntl < ntN) {
            const int e = (ntLo + ntl) * 16 + l15;
            if (e < BB) {
                const float be = bias2[e];
                #pragma unroll
                for (int mm = 0; mm < 4; ++mm) {
                    const int pr = mm * 16 + q * 4;
                    #pragma unroll
                    for (int r = 0; r < 4; ++r) {
                        float v = acc2[mm][ntl][r] + be + addsrc[(size_t)(pr + r) * BB + e];
                        sOut[(pr + r) * BB + e] = fb(v);
                    }
                }
            }
        }
    }
    __syncthreads();
}

// ---- fused MLP + scatter. blocks [0,2044): 64 pairs each; blocks [2044,2052): 64 diag rows.
// LDS = 64*392*2 + 512 = 50.7 KB -> 3 blocks/CU
__global__ __launch_bounds__(256, 3)
void ham_main(const float* __restrict__ nodes, const float* __restrict__ edges,
              const float* __restrict__ atomb, const float* __restrict__ ovl,
              const float* __restrict__ b1v, const float* __restrict__ b2v,
              const float* __restrict__ bo1, const float* __restrict__ bo2,
              const int* __restrict__ pair_i, const int* __restrict__ pair_j,
              const u16* __restrict__ ws, float* __restrict__ out)
{
    __shared__ u16 sX[ROWS * XS];    // X stage -> H tile -> Out tile (time-shared)
    __shared__ int sI[ROWS], sJ[ROWS];
    const int tid = threadIdx.x;
    const int bid = blockIdx.x;
    const bool isPair = bid < NPBLK;
    const int srow = tid >> 2;

    if (isPair && tid < ROWS) {
        int p = bid * ROWS + tid;
        sI[tid] = pair_i[p]; sJ[tid] = pair_j[p];
    }
    __syncthreads();

    if (isPair) {
        const int pbase = bid * ROWS;
        const int i = sI[srow], j = sJ[srow];
        mlp_tile<12>(nodes + (size_t)i * FDIM,
                     nodes + (size_t)j * FDIM,
                     edges + ((size_t)i * N_ATOMS + (size_t)j) * FDIM,
                     ws + OFF_WO1F, ws + OFF_WO2F, bo1, bo2,
                     ovl + (size_t)pbase * BB, sX, tid);

        u16* sOut = sX;
        // direct blocks H[i*14+a][j*14+b]: fixed a -> consecutive units are contiguous cols
        for (int u = tid; u < HALFU; u += 256) {
            const int a = u / 448;            // 448 = 64 pairs * 7 col-pairs
            const int r = u - a * 448;
            const int pl = r / 7;
            const int c2 = (r - pl * 7) * 2;
            const int i2 = sI[pl], j2 = sJ[pl];
            u32 v = *(const u32*)(const void*)(sOut + pl * BB + a * 14 + c2);
            float2 o; o.x = b2f((u16)v); o.y = b2f((u16)(v >> 16));
            size_t addr = (size_t)(i2 * 14 + a) * HROW + j2 * 14 + c2;
            *(float2*)(void*)(out + addr) = o;
        }
        // transposed blocks H[j*14+b][i*14+a]
        for (int u = tid; u < HALFU; u += 256) {
            const int pl = u / 98;
            const int r = u - pl * 98;
            const int b = r / 7;
            const int a2i = (r - b * 7) * 2;
            const int i2 = sI[pl], j2 = sJ[pl];
            float2 o;
            o.x = b2f(sOut[pl * BB + a2i * 14 + b]);
            o.y = b2f(sOut[pl * BB + (a2i + 1) * 14 + b]);
            size_t addr = (size_t)(j2 * 14 + b) * HROW + i2 * 14 + a2i;
            *(float2*)(void*)(out + addr) = o;
        }
    } else {
        const int nbase = (bid - NPBLK) * ROWS;
        const int nn = nbase + srow;
        const float* erow = edges + (size_t)nn * (N_ATOMS + 1) * FDIM;
        mlp_tile<8>(nodes + (size_t)nn * FDIM, erow, erow,
                    ws + OFF_W1F, ws + OFF_W2F, b1v, b2v,
                    atomb + (size_t)nbase * BB, sX, tid);

        u16* sOut = sX;
        for (int u = tid; u < HALFU; u += 256) {
            const int a = u / 448;
            const int r = u - a * 448;
            const int pl = r / 7;
            const int c2 = (r - pl * 7) * 2;
            const int n2 = nbase + pl;
            u32 v = *(const u32*)(const void*)(sOut + pl * BB + a * 14 + c2);
            float2 o; o.x = b2f((u16)v); o.y = b2f((u16)(v >> 16));
            size_t addr = (size_t)(n2 * 14 + a) * HROW + n2 * 14 + c2;
            *(float2*)(void*)(out + addr) = o;
        }
    }
}

extern "C" void kernel_launch(void* const* d_in, const int* in_sizes, int n_in,
                              void* d_out, int out_size, void* d_ws, size_t ws_size,
                              hipStream_t stream) {
    const float* nodes = (const float*)d_in[0];
    const float* edges = (const float*)d_in[1];
    const float* atomb = (const float*)d_in[2];
    const float* ovl   = (const float*)d_in[3];
    const float* W1    = (const float*)d_in[4];
    const float* b1    = (const float*)d_in[5];
    const float* W2    = (const float*)d_in[6];
    const float* b2    = (const float*)d_in[7];
    const float* Wo1   = (const float*)d_in[8];
    const float* bo1   = (const float*)d_in[9];
    const float* Wo2   = (const float*)d_in[10];
    const float* bo2   = (const float*)d_in[11];
    const int* pi      = (const int*)d_in[12];
    const int* pj      = (const int*)d_in[13];
    u16* ws    = (u16*)d_ws;
    float* out = (float*)d_out;

    prep_kernel<<<WS_ELEMS / 256, 256, 0, stream>>>(W1, W2, Wo1, Wo2, ws);
    ham_main<<<NBLK, 256, 0, stream>>>(nodes, edges, atomb, ovl,
                                       b1, b2, bo1, bo2, pi, pj, ws, out);
}